// Round 18
// baseline (229.346 us; speedup 1.0000x reference)
//
#include <hip/hip_runtime.h>
#include <hip/hip_bf16.h>

// B=256, N=10000, E=160000, H1=1024, H2=128
// Round 18: INSTRUMENTATION round. The harness poison-fills (39-41us) hide
// every kernel of ours in top-5; three neutral rounds say the cost model is
// wrong. pack_tiles repeats x5 and gather repeats x8 (idempotent, asm memory
// clobber per rep to defeat hoisting) so both enter top-5 WITH counters.
// total = base + 4*T_tiles + 7*T_gather; top-5 durations / reps give each.
// Round 19 reverts to the fastest structure and applies the findings.

#define KPAD 10240
#define NSTEPS 10
#define ZSPLIT 16
#define ELLW 64
#define NP 10240
#define TILE_REPS 5
#define GATHER_REPS 8

typedef __attribute__((ext_vector_type(8))) short short8v;
typedef __attribute__((ext_vector_type(4))) float f32x4;

__device__ inline short f2bf(float f) {
    union { float f; unsigned u; } v; v.f = f;
    unsigned r = v.u + 0x7fffu + ((v.u >> 16) & 1u);
    return (short)(r >> 16);
}

__device__ inline float bf2f(short s) {
    union { unsigned u; float f; } v;
    v.u = ((unsigned)(unsigned short)s) << 16;
    return v.f;
}

__device__ inline void gll16(const short* g, short* l) {
    __builtin_amdgcn_global_load_lds(
        (const __attribute__((address_space(1))) void*)g,
        (__attribute__((address_space(3))) void*)l, 16, 0, 0);
}

__global__ void zero_cnt(float4* __restrict__ p) {
    int i = blockIdx.x * blockDim.x + threadIdx.x;
    if (i < NP / 4) p[i] = make_float4(0.f, 0.f, 0.f, 0.f);
}

__global__ void fill_kernel(const int* __restrict__ ei, int* __restrict__ cnt,
                            int* __restrict__ ell, int E) {
    int e = blockIdx.x * blockDim.x + threadIdx.x;
    if (e >= E) return;
    int s = ei[e], d = ei[E + e];
    int c = atomicAdd(&cnt[d], 1);
    if (c < ELLW) ell[(d << 6) + c] = s;
}

// tiles only (r17 vectorized code), repeated TILE_REPS x for visibility
__global__ void pack_tiles(const float* __restrict__ data, const float* __restrict__ gw,
                           short* __restrict__ xwT, const float* __restrict__ W1,
                           short* __restrict__ W1T, int N, int B, int H1, int tTiles) {
    __shared__ short ldsbuf[18432];
    int id = blockIdx.x, t = threadIdx.x;
    for (int rep = 0; rep < TILE_REPS; ++rep) {
        asm volatile("" ::: "memory");   // defeat load hoisting across reps
        if (id < tTiles) {
            short (*lds1)[264] = (short(*)[264])ldsbuf;
            int n0 = id * 32;
            float wsc = gw[0];
            int br = t >> 3, lq = t & 7;
            bool full = (n0 + 32 <= N);
#pragma unroll
            for (int pass = 0; pass < 8; ++pass) {
                int b = pass * 32 + br;
                if (full) {
                    float4 v = *(const float4*)(data + (size_t)b * N + n0 + lq * 4);
                    lds1[lq * 4 + 0][b] = f2bf(v.x * wsc);
                    lds1[lq * 4 + 1][b] = f2bf(v.y * wsc);
                    lds1[lq * 4 + 2][b] = f2bf(v.z * wsc);
                    lds1[lq * 4 + 3][b] = f2bf(v.w * wsc);
                } else {
#pragma unroll
                    for (int jj = 0; jj < 4; ++jj) {
                        int n = n0 + lq * 4 + jj;
                        float v = (n < N) ? data[(size_t)b * N + n] : 0.f;
                        lds1[lq * 4 + jj][b] = f2bf(v * wsc);
                    }
                }
            }
            __syncthreads();
            int c = t & 31, nr = t >> 5;
#pragma unroll
            for (int pass = 0; pass < 4; ++pass) {
                int nl = pass * 8 + nr;
                int n = n0 + nl;
                if (n < N)
                    *(short8v*)(xwT + (size_t)n * B + c * 8) =
                        *(const short8v*)&lds1[nl][c * 8];
            }
        } else {
            short (*lds2)[72] = (short(*)[72])ldsbuf;
            int cc = id - tTiles;
            int nkx = KPAD >> 6;
            int kx = cc % nkx, hy = cc / nkx;
            int k0 = kx * 64, h0 = hy * 256;
            int w = t >> 6, l = t & 63;
#pragma unroll
            for (int pass = 0; pass < 16; ++pass) {
                int kr = pass * 4 + w;
                int k = k0 + kr;
                if (k < N) {
                    float4 v = *(const float4*)(W1 + (size_t)k * H1 + h0 + l * 4);
                    lds2[l * 4 + 0][kr] = f2bf(v.x);
                    lds2[l * 4 + 1][kr] = f2bf(v.y);
                    lds2[l * 4 + 2][kr] = f2bf(v.z);
                    lds2[l * 4 + 3][kr] = f2bf(v.w);
                } else {
                    lds2[l * 4 + 0][kr] = 0;
                    lds2[l * 4 + 1][kr] = 0;
                    lds2[l * 4 + 2][kr] = 0;
                    lds2[l * 4 + 3][kr] = 0;
                }
            }
            __syncthreads();
            int c = t & 7, hr = t >> 3;
#pragma unroll
            for (int pass = 0; pass < 8; ++pass) {
                int hl = pass * 32 + hr;
                *(short8v*)(W1T + (size_t)(h0 + hl) * KPAD + k0 + c * 8) =
                    *(const short8v*)&lds2[hl][c * 8];
            }
        }
        __syncthreads();   // LDS reuse across reps
    }
}

// one wave per dst row; repeated GATHER_REPS x for visibility
__global__ void gather_kernel(const int* __restrict__ cnt, const int* __restrict__ ell,
                              const float* __restrict__ gcn_b, const short* __restrict__ xwT,
                              short* __restrict__ A0, int N, int B) {
    int row = blockIdx.x * 4 + (threadIdx.x >> 6);
    if (row >= N) return;
    int lane = threadIdx.x & 63;
    const short4* x4 = (const short4*)xwT;
    const int B4 = B >> 2;
    for (int rep = 0; rep < GATHER_REPS; ++rep) {
        asm volatile("" ::: "memory");   // defeat CSE across reps
        float gb = gcn_b[0];
        int dcnt = cnt[row];
        float di = rsqrtf((float)dcnt + 1.0f);
        float w = di * di;
        short4 v = x4[(size_t)row * B4 + lane];
        float ax = bf2f(v.x) * w, ay = bf2f(v.y) * w;
        float az = bf2f(v.z) * w, aw = bf2f(v.w) * w;
        const int* er = ell + ((size_t)row << 6);
        int m = dcnt < ELLW ? dcnt : ELLW;
        int i = 0;
        for (; i + 1 < m; i += 2) {
            int s0 = er[i], s1 = er[i + 1];
            float n0 = rsqrtf((float)cnt[s0] + 1.0f) * di;
            float n1 = rsqrtf((float)cnt[s1] + 1.0f) * di;
            short4 u0 = x4[(size_t)s0 * B4 + lane];
            short4 u1 = x4[(size_t)s1 * B4 + lane];
            ax = fmaf(bf2f(u0.x), n0, ax); ay = fmaf(bf2f(u0.y), n0, ay);
            az = fmaf(bf2f(u0.z), n0, az); aw = fmaf(bf2f(u0.w), n0, aw);
            ax = fmaf(bf2f(u1.x), n1, ax); ay = fmaf(bf2f(u1.y), n1, ay);
            az = fmaf(bf2f(u1.z), n1, az); aw = fmaf(bf2f(u1.w), n1, aw);
        }
        if (i < m) {
            int s0 = er[i];
            float n0 = rsqrtf((float)cnt[s0] + 1.0f) * di;
            short4 u0 = x4[(size_t)s0 * B4 + lane];
            ax = fmaf(bf2f(u0.x), n0, ax); ay = fmaf(bf2f(u0.y), n0, ay);
            az = fmaf(bf2f(u0.z), n0, az); aw = fmaf(bf2f(u0.w), n0, aw);
        }
        short4 s4;
        s4.x = f2bf(fmaxf(ax + gb, 0.f));
        s4.y = f2bf(fmaxf(ay + gb, 0.f));
        s4.z = f2bf(fmaxf(az + gb, 0.f));
        s4.w = f2bf(fmaxf(aw + gb, 0.f));
        ((short4*)(A0 + (size_t)row * B))[lane] = s4;
    }
}

__global__ void convertA(const short* __restrict__ A0, short* __restrict__ A, int K, int M) {
    __shared__ short tile[32][34];
    int k0 = blockIdx.x * 32, m0 = blockIdx.y * 32;
    int tx = threadIdx.x, ty = threadIdx.y;
#pragma unroll
    for (int i = 0; i < 4; ++i) {
        int k = k0 + ty + i * 8;
        short v = (k < K) ? A0[(size_t)k * M + m0 + tx] : (short)0;
        tile[tx][ty + i * 8] = v;
    }
    __syncthreads();
#pragma unroll
    for (int i = 0; i < 4; ++i) {
        int m = m0 + ty + i * 8;
        A[(size_t)m * KPAD + k0 + tx] = tile[ty + i * 8][tx];
    }
}

__global__ void __launch_bounds__(512)
gemm1_mfma(const short* __restrict__ A, const short* __restrict__ Wt,
           float* __restrict__ hpart) {
    __shared__ __align__(16) short ldsA[2][8192];
    __shared__ __align__(16) short ldsB[2][8192];
    const int n0 = blockIdx.x * 128;
    const int m0 = blockIdx.y * 128;
    const int kz = blockIdx.z * (NSTEPS * 64);
    const int t = threadIdx.x;
    const int l = t & 63, w = t >> 6;
    const int wm = w >> 2, wn = w & 3;
    const int q = l >> 4, i16 = l & 15;

    const int sRow = t & 127, sKq = t >> 7;
    const short* gA = A + (size_t)(m0 + sRow) * KPAD + kz + sKq * 8;
    const short* gB = Wt + (size_t)(n0 + sRow) * KPAD + kz + sKq * 8;
    const int ld0 = w * 512;
    const int ld1 = 4096 + w * 512;

    f32x4 acc[4][2];
#pragma unroll
    for (int mi = 0; mi < 4; ++mi)
#pragma unroll
        for (int ni = 0; ni < 2; ++ni) acc[mi][ni] = (f32x4){0.f, 0.f, 0.f, 0.f};

    gll16(gA, &ldsA[0][ld0]); gll16(gA + 32, &ldsA[0][ld1]);
    gll16(gB, &ldsB[0][ld0]); gll16(gB + 32, &ldsB[0][ld1]);
    gA += 64; gB += 64;

    for (int ks = 0; ks < NSTEPS; ++ks) {
        const int cur = ks & 1;
        if (ks + 1 < NSTEPS) {
            gll16(gA, &ldsA[cur ^ 1][ld0]); gll16(gA + 32, &ldsA[cur ^ 1][ld1]);
            gll16(gB, &ldsB[cur ^ 1][ld0]); gll16(gB + 32, &ldsB[cur ^ 1][ld1]);
            gA += 64; gB += 64;
            asm volatile("s_waitcnt vmcnt(4)" ::: "memory");
        } else {
            asm volatile("s_waitcnt vmcnt(0)" ::: "memory");
        }
        __builtin_amdgcn_s_barrier();
        __builtin_amdgcn_sched_barrier(0);
        const short* bA = &ldsA[cur][0];
        const short* bB = &ldsB[cur][0];
#pragma unroll
        for (int kh = 0; kh < 2; ++kh) {
            const int kq = kh * 4 + q;
            short8v a[4], b[2];
#pragma unroll
            for (int mi = 0; mi < 4; ++mi)
                a[mi] = *(const short8v*)&bA[kq * 1024 + (wm * 64 + mi * 16 + i16) * 8];
#pragma unroll
            for (int ni = 0; ni < 2; ++ni)
                b[ni] = *(const short8v*)&bB[kq * 1024 + (wn * 32 + ni * 16 + i16) * 8];
#pragma unroll
            for (int mi = 0; mi < 4; ++mi)
#pragma unroll
                for (int ni = 0; ni < 2; ++ni)
                    acc[mi][ni] = __builtin_amdgcn_mfma_f32_16x16x32_bf16(a[mi], b[ni], acc[mi][ni], 0, 0, 0);
        }
        __builtin_amdgcn_s_barrier();
    }

    float* hp = hpart + (size_t)blockIdx.z * (256 * 1024);
#pragma unroll
    for (int mi = 0; mi < 4; ++mi) {
#pragma unroll
        for (int ni = 0; ni < 2; ++ni) {
#pragma unroll
            for (int r = 0; r < 4; ++r) {
                int mr = m0 + wm * 64 + mi * 16 + q * 4 + r;
                int nc = n0 + wn * 32 + ni * 16 + i16;
                hp[(size_t)mr * 1024 + nc] = acc[mi][ni][r];
            }
        }
    }
}

__global__ void gemm2_fused(const float* __restrict__ hpart, const float* __restrict__ b1,
                            const float* __restrict__ W2, const float* __restrict__ b2,
                            float* __restrict__ out, int Z) {
    __shared__ float h_lds[1024];
    __shared__ float partial[8][128];
    int b = blockIdx.x, t = threadIdx.x;
    float s = 0.f;
    for (int z = 0; z < Z; ++z) s += hpart[(size_t)z * (256 * 1024) + b * 1024 + t];
    h_lds[t] = fmaxf(s + b1[t], 0.f);
    __syncthreads();
    int j = t & 127, oct = t >> 7;
    const float* w2p = W2 + (size_t)oct * 128 * 128 + j;
    const float* hp = h_lds + oct * 128;
    float s0 = 0.f, s1 = 0.f, s2 = 0.f, s3 = 0.f;
#pragma unroll 8
    for (int k = 0; k < 128; k += 4) {
        s0 = fmaf(hp[k],     w2p[(size_t)k * 128],       s0);
        s1 = fmaf(hp[k + 1], w2p[(size_t)(k + 1) * 128], s1);
        s2 = fmaf(hp[k + 2], w2p[(size_t)(k + 2) * 128], s2);
        s3 = fmaf(hp[k + 3], w2p[(size_t)(k + 3) * 128], s3);
    }
    partial[oct][j] = (s0 + s1) + (s2 + s3);
    __syncthreads();
    if (t < 128) {
        float v = b2[t];
#pragma unroll
        for (int o = 0; o < 8; ++o) v += partial[o][t];
        out[(size_t)b * 128 + t] = fmaxf(v, 0.f);
    }
}

extern "C" void kernel_launch(void* const* d_in, const int* in_sizes, int n_in,
                              void* d_out, int out_size, void* d_ws, size_t ws_size,
                              hipStream_t stream) {
    const float* data = (const float*)d_in[0];
    const float* gw   = (const float*)d_in[1];
    const float* gb   = (const float*)d_in[2];
    const float* W1   = (const float*)d_in[3];
    const float* b1   = (const float*)d_in[4];
    const float* W2   = (const float*)d_in[5];
    const float* b2   = (const float*)d_in[6];
    const int*   ei   = (const int*)d_in[7];
    float* out = (float*)d_out;

    const int B  = 256;
    const int H1 = in_sizes[4];
    const int H2 = in_sizes[6];
    const int N  = in_sizes[3] / H1;
    const int E  = in_sizes[7] / 2;
    (void)H2;

    int* iws = (int*)d_ws;
    int*   cnt  = iws;
    int*   ell  = cnt + NP;
    short* S    = (short*)(ell + (size_t)NP * ELLW);
    short* A    = S;
    short* W1T  = A + (size_t)256 * KPAD;
    short* xwT  = W1T + (size_t)1024 * KPAD;
    short* A0   = xwT + (size_t)N * B;
    float* hpart = (float*)xwT;

    const int tTiles = (N + 31) / 32;                // 313
    const int cTiles = (KPAD / 64) * (H1 / 256);     // 640

    zero_cnt<<<(NP / 4 + 255) / 256, 256, 0, stream>>>((float4*)cnt);

    fill_kernel<<<(E + 255) / 256, 256, 0, stream>>>(ei, cnt, ell, E);

    pack_tiles<<<tTiles + cTiles, 256, 0, stream>>>(data, gw, xwT, W1, W1T, N, B, H1, tTiles);

    gather_kernel<<<(N + 3) / 4, 256, 0, stream>>>(cnt, ell, gb, xwT, A0, N, B);

    convertA<<<dim3(KPAD / 32, B / 32), dim3(32, 8), 0, stream>>>(A0, A, N, B);

    dim3 g1(H1 / 128, B / 128, ZSPLIT);
    gemm1_mfma<<<g1, 512, 0, stream>>>(A, W1T, hpart);

    gemm2_fused<<<B, 1024, 0, stream>>>(hpart, b1, W2, b2, out, ZSPLIT);
}